// Round 1
// baseline (933.402 us; speedup 1.0000x reference)
//
#include <hip/hip_runtime.h>
#include <cstdint>

#define DEV static __device__ __forceinline__

typedef __attribute__((ext_vector_type(8))) short short8v;     // 8 x bf16 bits
typedef __attribute__((ext_vector_type(4))) float f32x4;
typedef __attribute__((ext_vector_type(4))) float fl4;
typedef __attribute__((ext_vector_type(4))) unsigned short us4;
typedef __attribute__((ext_vector_type(8))) unsigned short us8;

DEV float b2f(unsigned short u) {
  union { unsigned int i; float f; } c; c.i = ((unsigned int)u) << 16; return c.f;
}
DEV unsigned short f2b(float f) {   // RNE float -> bf16 bits
  union { float f; unsigned int i; } c; c.f = f;
  unsigned int u = c.i;
  u += 0x7fffu + ((u >> 16) & 1u);
  return (unsigned short)(u >> 16);
}

DEV void gload16(const void* g, void* l) {  // async global->LDS, 16B/lane
  __builtin_amdgcn_global_load_lds(
      (const __attribute__((address_space(1))) unsigned int*)g,
      (__attribute__((address_space(3))) unsigned int*)l, 16, 0, 0);
}

// ---------------- elementwise f32 -> bf16 ----------------
__global__ __launch_bounds__(256) void k_f32_to_bf16(const float* __restrict__ src,
                                                     unsigned short* __restrict__ dst, long n) {
  long i = ((long)blockIdx.x * 256 + threadIdx.x) * 4;
  if (i >= n) return;
  fl4 v = *(const fl4*)(src + i);
  us4 o;
  o[0] = f2b(v[0]); o[1] = f2b(v[1]); o[2] = f2b(v[2]); o[3] = f2b(v[3]);
  *(us4*)(dst + i) = o;
}

// ---------------- column sum-of-squares partials (over C chunks) ----------------
// grid (16 chunks, 16 batches), 256 thr, 4 l per thread
__global__ __launch_bounds__(256) void k_norms_part(const unsigned short* __restrict__ Q,
                                                    const unsigned short* __restrict__ K,
                                                    float* __restrict__ pq, float* __restrict__ pk) {
  const int ch = blockIdx.x, b = blockIdx.y;
  const int l0 = threadIdx.x * 4;
  float aq[4] = {0.f,0.f,0.f,0.f}, ak[4] = {0.f,0.f,0.f,0.f};
  long base = ((long)b * 2048 + (long)ch * 128) * 1024 + l0;
  for (int c = 0; c < 128; ++c, base += 1024) {
    us4 q = *(const us4*)(Q + base);
    us4 k = *(const us4*)(K + base);
#pragma unroll
    for (int j = 0; j < 4; ++j) {
      float fq = b2f(q[j]); aq[j] += fq * fq;
      float fk = b2f(k[j]); ak[j] += fk * fk;
    }
  }
  long o = ((long)b * 16 + ch) * 1024 + l0;
#pragma unroll
  for (int j = 0; j < 4; ++j) { pq[o + j] = aq[j]; pk[o + j] = ak[j]; }
}

__global__ __launch_bounds__(256) void k_norms_fin(const float* __restrict__ pq,
                                                   const float* __restrict__ pk,
                                                   float* __restrict__ invq, float* __restrict__ invk) {
  const int gid = blockIdx.x * 256 + threadIdx.x;   // 16384
  const int b = gid >> 10, l = gid & 1023;
  float sq = 0.f, sk = 0.f;
  for (int ch = 0; ch < 16; ++ch) {
    long o = ((long)b * 16 + ch) * 1024 + l;
    sq += pq[o]; sk += pk[o];
  }
  invq[gid] = 1.0f / sqrtf(sq);
  invk[gid] = 1.0f / sqrtf(sk);
}

// ---------------- per-row: Knorm (bf16), Ksum = sum_l Kh*invk, Vsum = sum_l Vh ----------------
// one wave per row; 8192 blocks x 4 waves = 32768 rows
__global__ __launch_bounds__(256) void k_rows(const unsigned short* __restrict__ Kh,
                                              const unsigned short* __restrict__ Vh,
                                              const float* __restrict__ invk,
                                              unsigned short* __restrict__ Kn,
                                              float* __restrict__ Ksum, float* __restrict__ Vsum) {
  const int wid = threadIdx.x >> 6, lane = threadIdx.x & 63;
  const long r = (long)blockIdx.x * 4 + wid;
  const int b = (int)(r >> 11);
  const long base = r * 1024 + lane * 16;
  const float* ik = invk + (long)b * 1024 + lane * 16;
  float ks = 0.f, vs = 0.f;
#pragma unroll
  for (int h = 0; h < 2; ++h) {
    us8 kv = *(const us8*)(Kh + base + h * 8);
    us8 vv = *(const us8*)(Vh + base + h * 8);
    unsigned short outb[8];
#pragma unroll
    for (int j = 0; j < 8; ++j) {
      float kf = b2f(kv[j]) * ik[h * 8 + j];
      ks += kf; outb[j] = f2b(kf);
      vs += b2f(vv[j]);
    }
    *(us8*)(Kn + base + h * 8) = *(const us8*)outb;
  }
#pragma unroll
  for (int off = 32; off > 0; off >>= 1) {
    ks += __shfl_down(ks, off);
    vs += __shfl_down(vs, off);
  }
  if (lane == 0) { Ksum[r] = ks; Vsum[r] = vs; }
}

// ---------------- transpose Q (B,C,L) -> QT (B,L,C), 64x64 tiles ----------------
__global__ __launch_bounds__(256) void k_transpose(const unsigned short* __restrict__ Q,
                                                   unsigned short* __restrict__ QT) {
  __shared__ unsigned short tile[64][68];
  const int c0 = blockIdx.x * 64, n0 = blockIdx.y * 64, b = blockIdx.z;
  const int jr = (threadIdx.x & 15) * 4;
  const int ir = threadIdx.x >> 4;
  const unsigned short* src = Q + ((long)b * 2048 + c0) * 1024 + n0;
#pragma unroll
  for (int p = 0; p < 4; ++p) {
    int i = ir + p * 16;
    *(us4*)&tile[i][jr] = *(const us4*)(src + (long)i * 1024 + jr);
  }
  __syncthreads();
  unsigned short* dst = QT + ((long)b * 1024 + n0) * 2048 + c0;
#pragma unroll
  for (int p = 0; p < 4; ++p) {
    int j = ir + p * 16;
    us4 o;
    o[0] = tile[jr + 0][j]; o[1] = tile[jr + 1][j];
    o[2] = tile[jr + 2][j]; o[3] = tile[jr + 3][j];
    *(us4*)(dst + (long)j * 2048 + jr) = o;
  }
}

// ---------------- tailor partials: sum_c Qh[c][n]*(Ksum[c]+eps) ----------------
__global__ __launch_bounds__(256) void k_tailor_part(const unsigned short* __restrict__ Q,
                                                     const float* __restrict__ Ksum,
                                                     float* __restrict__ tp) {
  const int ch = blockIdx.x, b = blockIdx.y;
  const int l0 = threadIdx.x * 4;
  float a[4] = {0.f,0.f,0.f,0.f};
  long base = ((long)b * 2048 + (long)ch * 128) * 1024 + l0;
  const float* ks = Ksum + (long)b * 2048 + ch * 128;
  for (int c = 0; c < 128; ++c, base += 1024) {
    float w = ks[c] + 1e-6f;
    us4 q = *(const us4*)(Q + base);
#pragma unroll
    for (int j = 0; j < 4; ++j) a[j] += b2f(q[j]) * w;
  }
  long o = ((long)b * 16 + ch) * 1024 + l0;
#pragma unroll
  for (int j = 0; j < 4; ++j) tp[o + j] = a[j];
}

__global__ __launch_bounds__(256) void k_tailor_fin(const float* __restrict__ tp,
                                                    const float* __restrict__ invq,
                                                    float* __restrict__ tailor) {
  const int gid = blockIdx.x * 256 + threadIdx.x;   // 16384
  const int b = gid >> 10, l = gid & 1023;
  float s = 0.f;
  for (int ch = 0; ch < 16; ++ch) s += tp[((long)b * 16 + ch) * 1024 + l];
  tailor[gid] = 1.0f / (1024.0f + invq[gid] * s);
}

// ---------------- NT GEMM: C[m][n] = sum_k A[m][k] * Bt[n][k]  (both K-contiguous) ----------------
// 128x128 tile, BK=32, 4 waves (2x2), each wave 64x64 via 4x4 MFMA 16x16x32 bf16.
// EPI 0: bf16 out (+optional fp32 bias[col]).  EPI 1: fused final fp32 epilogue.
template<int EPI>
__global__ __launch_bounds__(256)
void k_gemm_bt(const unsigned short* __restrict__ A,
               const unsigned short* __restrict__ Bt,
               void* __restrict__ Cout,
               int N, int K,
               long sA, long sB, long sC,
               const float* __restrict__ bias,
               const float* __restrict__ xin,
               const float* __restrict__ Vsum,
               const float* __restrict__ invq,
               const float* __restrict__ tailor,
               const float* __restrict__ gptr) {
  __shared__ __align__(16) unsigned short As[128 * 32];
  __shared__ __align__(16) unsigned short Bs[128 * 32];

  const int tid = threadIdx.x;
  const int wid = tid >> 6, lane = tid & 63;
  const int wr = wid >> 1, wc = wid & 1;
  const int l15 = lane & 15, lk = lane >> 4;

  // XCD-bijective swizzle over (x,y); nwg % 8 == 0 for all our grids
  const int nx = gridDim.x;
  const int nwg = nx * gridDim.y;
  const int lin = blockIdx.y * nx + blockIdx.x;
  const int cpx = nwg >> 3;
  const int wg = (lin & 7) * cpx + (lin >> 3);
  const int bn = wg % nx;
  const int bm = wg / nx;
  const int bz = blockIdx.z;

  const unsigned short* Ab = A + (long)bz * sA + (long)bm * 128 * K;
  const unsigned short* Bb = Bt + (long)bz * sB + (long)bn * 128 * K;

  const long soff = (long)(wid * 16 + (lane >> 2)) * K + (long)(lane & 3) * 8;

  f32x4 acc[4][4];
#pragma unroll
  for (int i = 0; i < 4; ++i)
#pragma unroll
    for (int j = 0; j < 4; ++j) acc[i][j] = (f32x4){0.f, 0.f, 0.f, 0.f};

  for (int k0 = 0; k0 < K; k0 += 32) {
    __syncthreads();
    gload16(Ab + soff + k0,                 As + wid * 512);
    gload16(Ab + soff + 64 * (long)K + k0,  As + 2048 + wid * 512);
    gload16(Bb + soff + k0,                 Bs + wid * 512);
    gload16(Bb + soff + 64 * (long)K + k0,  Bs + 2048 + wid * 512);
    __syncthreads();

    short8v af[4], bfr[4];
#pragma unroll
    for (int i = 0; i < 4; ++i)
      af[i] = *(const short8v*)(As + (wr * 64 + i * 16 + l15) * 32 + lk * 8);
#pragma unroll
    for (int j = 0; j < 4; ++j)
      bfr[j] = *(const short8v*)(Bs + (wc * 64 + j * 16 + l15) * 32 + lk * 8);
#pragma unroll
    for (int i = 0; i < 4; ++i)
#pragma unroll
      for (int j = 0; j < 4; ++j)
        acc[i][j] = __builtin_amdgcn_mfma_f32_16x16x32_bf16(af[i], bfr[j], acc[i][j], 0, 0, 0);
  }

  const int row0 = bm * 128 + wr * 64;
  const int col0 = bn * 128 + wc * 64;

  if constexpr (EPI == 0) {
    unsigned short* Cb = (unsigned short*)Cout + (long)bz * sC;
#pragma unroll
    for (int i = 0; i < 4; ++i)
#pragma unroll
      for (int j = 0; j < 4; ++j) {
        const int col = col0 + j * 16 + l15;
        const float bv = bias ? bias[col] : 0.0f;
#pragma unroll
        for (int r = 0; r < 4; ++r) {
          const int row = row0 + i * 16 + lk * 4 + r;
          Cb[(long)row * N + col] = f2b(acc[i][j][r] + bv);
        }
      }
  } else {
    float* Cb = (float*)Cout + (long)bz * sC;
    const float g = gptr[0];
#pragma unroll
    for (int i = 0; i < 4; ++i)
#pragma unroll
      for (int j = 0; j < 4; ++j) {
        const int col = col0 + j * 16 + l15;
        const float iq = invq[bz * 1024 + col];
        const float tl = tailor[bz * 1024 + col];
#pragma unroll
        for (int r = 0; r < 4; ++r) {
          const int row = row0 + i * 16 + lk * 4 + r;
          const long idx = ((long)bz * 2048 + row) * 1024 + col;
          Cb[(long)row * N + col] = xin[idx] + g * ((Vsum[bz * 2048 + row] + iq * acc[i][j][r]) * tl);
        }
      }
  }
}

extern "C" void kernel_launch(void* const* d_in, const int* in_sizes, int n_in,
                              void* d_out, int out_size, void* d_ws, size_t ws_size,
                              hipStream_t stream) {
  (void)in_sizes; (void)n_in; (void)out_size;
  const float* x     = (const float*)d_in[0];
  const float* Wq    = (const float*)d_in[1];
  const float* bq    = (const float*)d_in[2];
  const float* Wk    = (const float*)d_in[3];
  const float* bk    = (const float*)d_in[4];
  const float* Wv    = (const float*)d_in[5];
  const float* bv    = (const float*)d_in[6];
  const float* gamma = (const float*)d_in[7];

  // B=16, C=2048, L=D=1024
  const long NE = 16L * 2048 * 1024;          // 33,554,432 elements
  const long BUF = NE * 2;                    // 67,108,864 bytes per bf16 tensor

  char* w = (char*)d_ws;
  unsigned short* Qh  = (unsigned short*)(w);
  unsigned short* Kh  = (unsigned short*)(w + BUF);
  unsigned short* Vh  = (unsigned short*)(w + 2 * BUF);
  unsigned short* Kn  = (unsigned short*)(w + 3 * BUF);
  unsigned short* XQT = (unsigned short*)(w + 4 * BUF);  // xh, later overlaid by QT
  unsigned short* M2  = (unsigned short*)(w);            // overlays Qh+Kh (dead by then)
  size_t off = 5 * (size_t)BUF;
  unsigned short* Wqh = (unsigned short*)(w + off); off += 2097152;
  unsigned short* Wkh = (unsigned short*)(w + off); off += 2097152;
  unsigned short* Wvh = (unsigned short*)(w + off); off += 2097152;
  float* pq     = (float*)(w + off); off += 1048576;
  float* pk     = (float*)(w + off); off += 1048576;
  float* tp     = (float*)(w + off); off += 1048576;
  float* invq   = (float*)(w + off); off += 65536;
  float* invk   = (float*)(w + off); off += 65536;
  float* tailor = (float*)(w + off); off += 65536;
  float* Ksum   = (float*)(w + off); off += 131072;
  float* Vsum   = (float*)(w + off); off += 131072;
  if (ws_size < off) return;  // workspace too small -> fail loudly at validation

  unsigned short* xh = XQT;

  // 1) casts
  k_f32_to_bf16<<<dim3((unsigned)(NE / 1024)), 256, 0, stream>>>(x, xh, NE);
  k_f32_to_bf16<<<dim3(1024), 256, 0, stream>>>(Wq, Wqh, 1048576);
  k_f32_to_bf16<<<dim3(1024), 256, 0, stream>>>(Wk, Wkh, 1048576);
  k_f32_to_bf16<<<dim3(1024), 256, 0, stream>>>(Wv, Wvh, 1048576);

  // 2) Q/K/V = x @ W^T + b   (M=32768, N=1024, K=1024; NT layout)
  dim3 g1(8, 256, 1);
  k_gemm_bt<0><<<g1, 256, 0, stream>>>(xh, Wqh, Qh, 1024, 1024, 0, 0, 0, bq,
                                       nullptr, nullptr, nullptr, nullptr, nullptr);
  k_gemm_bt<0><<<g1, 256, 0, stream>>>(xh, Wkh, Kh, 1024, 1024, 0, 0, 0, bk,
                                       nullptr, nullptr, nullptr, nullptr, nullptr);
  k_gemm_bt<0><<<g1, 256, 0, stream>>>(xh, Wvh, Vh, 1024, 1024, 0, 0, 0, bv,
                                       nullptr, nullptr, nullptr, nullptr, nullptr);

  // 3) column L2 norms of Q,K over C
  k_norms_part<<<dim3(16, 16), 256, 0, stream>>>(Qh, Kh, pq, pk);
  k_norms_fin<<<dim3(64), 256, 0, stream>>>(pq, pk, invq, invk);

  // 4) Knorm, Ksum, Vsum
  k_rows<<<dim3(8192), 256, 0, stream>>>(Kh, Vh, invk, Kn, Ksum, Vsum);

  // 5) QT = Q^T per batch (overlays xh; all GEMM1 done)
  k_transpose<<<dim3(32, 16, 16), 256, 0, stream>>>(Qh, XQT);

  // 6) tailor
  k_tailor_part<<<dim3(16, 16), 256, 0, stream>>>(Qh, Ksum, tp);
  k_tailor_fin<<<dim3(64), 256, 0, stream>>>(tp, invq, tailor);

  // 7) M2[c][m] = sum_n V[c,n] * Knorm[m,n]   (per batch, M=N=2048, K=1024)
  k_gemm_bt<0><<<dim3(16, 16, 16), 256, 0, stream>>>(
      Vh, Kn, M2, 2048, 1024, 2048L * 1024, 2048L * 1024, 2048L * 2048, nullptr,
      nullptr, nullptr, nullptr, nullptr, nullptr);

  // 8) out[c][n] = x + gamma*(Vsum[c] + invq[n]*sum_m M2[c,m]*QT[n,m]) * tailor[n]
  k_gemm_bt<1><<<dim3(8, 16, 16), 256, 0, stream>>>(
      M2, XQT, d_out, 1024, 2048, 2048L * 2048, 1024L * 2048, 2048L * 1024, nullptr,
      x, Vsum, invq, tailor, gamma);
}

// Round 2
// 743.707 us; speedup vs baseline: 1.2551x; 1.2551x over previous
//
#include <hip/hip_runtime.h>
#include <cstdint>

#define DEV static __device__ __forceinline__

typedef __attribute__((ext_vector_type(8))) short short8v;     // 8 x bf16 bits
typedef __attribute__((ext_vector_type(4))) float f32x4;
typedef __attribute__((ext_vector_type(4))) float fl4;
typedef __attribute__((ext_vector_type(4))) unsigned short us4;
typedef __attribute__((ext_vector_type(8))) unsigned short us8;

DEV float b2f(unsigned short u) {
  union { unsigned int i; float f; } c; c.i = ((unsigned int)u) << 16; return c.f;
}
DEV unsigned short f2b(float f) {   // RNE float -> bf16 bits
  union { float f; unsigned int i; } c; c.f = f;
  unsigned int u = c.i;
  u += 0x7fffu + ((u >> 16) & 1u);
  return (unsigned short)(u >> 16);
}

DEV void gload16(const void* g, void* l) {  // async global->LDS, 16B/lane
  __builtin_amdgcn_global_load_lds(
      (const __attribute__((address_space(1))) unsigned int*)g,
      (__attribute__((address_space(3))) unsigned int*)l, 16, 0, 0);
}

// ---------------- elementwise f32 -> bf16 ----------------
__global__ __launch_bounds__(256) void k_f32_to_bf16(const float* __restrict__ src,
                                                     unsigned short* __restrict__ dst, long n) {
  long i = ((long)blockIdx.x * 256 + threadIdx.x) * 4;
  if (i >= n) return;
  fl4 v = *(const fl4*)(src + i);
  us4 o;
  o[0] = f2b(v[0]); o[1] = f2b(v[1]); o[2] = f2b(v[2]); o[3] = f2b(v[3]);
  *(us4*)(dst + i) = o;
}

// ---------------- column sum-of-squares partials (over C chunks) ----------------
// grid (16 chunks, 16 batches), 256 thr, 4 l per thread
__global__ __launch_bounds__(256) void k_norms_part(const unsigned short* __restrict__ Q,
                                                    const unsigned short* __restrict__ K,
                                                    float* __restrict__ pq, float* __restrict__ pk) {
  const int ch = blockIdx.x, b = blockIdx.y;
  const int l0 = threadIdx.x * 4;
  float aq[4] = {0.f,0.f,0.f,0.f}, ak[4] = {0.f,0.f,0.f,0.f};
  long base = ((long)b * 2048 + (long)ch * 128) * 1024 + l0;
  for (int c = 0; c < 128; ++c, base += 1024) {
    us4 q = *(const us4*)(Q + base);
    us4 k = *(const us4*)(K + base);
#pragma unroll
    for (int j = 0; j < 4; ++j) {
      float fq = b2f(q[j]); aq[j] += fq * fq;
      float fk = b2f(k[j]); ak[j] += fk * fk;
    }
  }
  long o = ((long)b * 16 + ch) * 1024 + l0;
#pragma unroll
  for (int j = 0; j < 4; ++j) { pq[o + j] = aq[j]; pk[o + j] = ak[j]; }
}

__global__ __launch_bounds__(256) void k_norms_fin(const float* __restrict__ pq,
                                                   const float* __restrict__ pk,
                                                   float* __restrict__ invq, float* __restrict__ invk) {
  const int gid = blockIdx.x * 256 + threadIdx.x;   // 16384
  const int b = gid >> 10, l = gid & 1023;
  float sq = 0.f, sk = 0.f;
  for (int ch = 0; ch < 16; ++ch) {
    long o = ((long)b * 16 + ch) * 1024 + l;
    sq += pq[o]; sk += pk[o];
  }
  invq[gid] = 1.0f / sqrtf(sq);
  invk[gid] = 1.0f / sqrtf(sk);
}

// ---------------- per-row sums: Ksum = sum_l Kh*invk[l], Vsum = sum_l Vh ----------------
// one wave per row; 8192 blocks x 4 waves = 32768 rows
__global__ __launch_bounds__(256) void k_rowsums(const unsigned short* __restrict__ Kh,
                                                 const unsigned short* __restrict__ Vh,
                                                 const float* __restrict__ invk,
                                                 float* __restrict__ Ksum, float* __restrict__ Vsum) {
  const int wid = threadIdx.x >> 6, lane = threadIdx.x & 63;
  const long r = (long)blockIdx.x * 4 + wid;
  const int b = (int)(r >> 11);
  const long base = r * 1024 + lane * 16;
  const float* ik = invk + (long)b * 1024 + lane * 16;
  float ks = 0.f, vs = 0.f;
#pragma unroll
  for (int h = 0; h < 2; ++h) {
    us8 kv = *(const us8*)(Kh + base + h * 8);
    us8 vv = *(const us8*)(Vh + base + h * 8);
#pragma unroll
    for (int j = 0; j < 8; ++j) {
      ks += b2f(kv[j]) * ik[h * 8 + j];
      vs += b2f(vv[j]);
    }
  }
#pragma unroll
  for (int off = 32; off > 0; off >>= 1) {
    ks += __shfl_down(ks, off);
    vs += __shfl_down(vs, off);
  }
  if (lane == 0) { Ksum[r] = ks; Vsum[r] = vs; }
}

// ---------------- transpose+scale: (B,C=2048,L=1024) -> (B,L,C), dst row j scaled by s[b*1024+j] ----------------
__global__ __launch_bounds__(256) void k_transpose_scale(const unsigned short* __restrict__ Q,
                                                         const float* __restrict__ scale,
                                                         unsigned short* __restrict__ QT) {
  __shared__ unsigned short tile[64][68];
  const int c0 = blockIdx.x * 64, n0 = blockIdx.y * 64, b = blockIdx.z;
  const int jr = (threadIdx.x & 15) * 4;
  const int ir = threadIdx.x >> 4;
  const unsigned short* src = Q + ((long)b * 2048 + c0) * 1024 + n0;
#pragma unroll
  for (int p = 0; p < 4; ++p) {
    int i = ir + p * 16;
    *(us4*)&tile[i][jr] = *(const us4*)(src + (long)i * 1024 + jr);
  }
  __syncthreads();
  unsigned short* dst = QT + ((long)b * 1024 + n0) * 2048 + c0;
#pragma unroll
  for (int p = 0; p < 4; ++p) {
    int j = ir + p * 16;
    const float s = scale[b * 1024 + n0 + j];
    us4 o;
    o[0] = f2b(b2f(tile[jr + 0][j]) * s);
    o[1] = f2b(b2f(tile[jr + 1][j]) * s);
    o[2] = f2b(b2f(tile[jr + 2][j]) * s);
    o[3] = f2b(b2f(tile[jr + 3][j]) * s);
    *(us4*)(dst + (long)j * 2048 + jr) = o;
  }
}

// ---------------- tailor partials: sum_c Qh[c][n]*(Ksum[c]+eps) ----------------
__global__ __launch_bounds__(256) void k_tailor_part(const unsigned short* __restrict__ Q,
                                                     const float* __restrict__ Ksum,
                                                     float* __restrict__ tp) {
  const int ch = blockIdx.x, b = blockIdx.y;
  const int l0 = threadIdx.x * 4;
  float a[4] = {0.f,0.f,0.f,0.f};
  long base = ((long)b * 2048 + (long)ch * 128) * 1024 + l0;
  const float* ks = Ksum + (long)b * 2048 + ch * 128;
  for (int c = 0; c < 128; ++c, base += 1024) {
    float w = ks[c] + 1e-6f;
    us4 q = *(const us4*)(Q + base);
#pragma unroll
    for (int j = 0; j < 4; ++j) a[j] += b2f(q[j]) * w;
  }
  long o = ((long)b * 16 + ch) * 1024 + l0;
#pragma unroll
  for (int j = 0; j < 4; ++j) tp[o + j] = a[j];
}

__global__ __launch_bounds__(256) void k_tailor_fin(const float* __restrict__ tp,
                                                    const float* __restrict__ invq,
                                                    float* __restrict__ tailor) {
  const int gid = blockIdx.x * 256 + threadIdx.x;   // 16384
  const int b = gid >> 10, l = gid & 1023;
  float s = 0.f;
  for (int ch = 0; ch < 16; ++ch) s += tp[((long)b * 16 + ch) * 1024 + l];
  tailor[gid] = 1.0f / (1024.0f + invq[gid] * s);
}

// ---------------- NT GEMM: C[m][n] = sum_k A[m][k] * Bt[n][k]  (both K-contiguous) ----------------
// 128x128 tile, BK=32, 4 waves (2x2), each wave 64x64 via 4x4 MFMA 16x16x32 bf16.
// EPI 0: bf16 out (+optional fp32 bias[col]).  EPI 1: fused final fp32 epilogue.
template<int EPI>
__global__ __launch_bounds__(256)
void k_gemm_bt(const unsigned short* __restrict__ A,
               const unsigned short* __restrict__ Bt,
               void* __restrict__ Cout,
               int N, int K,
               long sA, long sB, long sC,
               const float* __restrict__ bias,
               const float* __restrict__ xin,
               const float* __restrict__ Vsum,
               const float* __restrict__ tailor,
               const float* __restrict__ gptr) {
  __shared__ __align__(16) unsigned short As[128 * 32];
  __shared__ __align__(16) unsigned short Bs[128 * 32];

  const int tid = threadIdx.x;
  const int wid = tid >> 6, lane = tid & 63;
  const int wr = wid >> 1, wc = wid & 1;
  const int l15 = lane & 15, lk = lane >> 4;

  // XCD-bijective swizzle over (x,y); nwg % 8 == 0 for all our grids
  const int nx = gridDim.x;
  const int nwg = nx * gridDim.y;
  const int lin = blockIdx.y * nx + blockIdx.x;
  const int cpx = nwg >> 3;
  const int wg = (lin & 7) * cpx + (lin >> 3);
  const int bn = wg % nx;
  const int bm = wg / nx;
  const int bz = blockIdx.z;

  const unsigned short* Ab = A + (long)bz * sA + (long)bm * 128 * K;
  const unsigned short* Bb = Bt + (long)bz * sB + (long)bn * 128 * K;

  const long soff = (long)(wid * 16 + (lane >> 2)) * K + (long)(lane & 3) * 8;

  f32x4 acc[4][4];
#pragma unroll
  for (int i = 0; i < 4; ++i)
#pragma unroll
    for (int j = 0; j < 4; ++j) acc[i][j] = (f32x4){0.f, 0.f, 0.f, 0.f};

  for (int k0 = 0; k0 < K; k0 += 32) {
    __syncthreads();
    gload16(Ab + soff + k0,                 As + wid * 512);
    gload16(Ab + soff + 64 * (long)K + k0,  As + 2048 + wid * 512);
    gload16(Bb + soff + k0,                 Bs + wid * 512);
    gload16(Bb + soff + 64 * (long)K + k0,  Bs + 2048 + wid * 512);
    __syncthreads();

    short8v af[4], bfr[4];
#pragma unroll
    for (int i = 0; i < 4; ++i)
      af[i] = *(const short8v*)(As + (wr * 64 + i * 16 + l15) * 32 + lk * 8);
#pragma unroll
    for (int j = 0; j < 4; ++j)
      bfr[j] = *(const short8v*)(Bs + (wc * 64 + j * 16 + l15) * 32 + lk * 8);
#pragma unroll
    for (int i = 0; i < 4; ++i)
#pragma unroll
      for (int j = 0; j < 4; ++j)
        acc[i][j] = __builtin_amdgcn_mfma_f32_16x16x32_bf16(af[i], bfr[j], acc[i][j], 0, 0, 0);
  }

  const int row0 = bm * 128 + wr * 64;
  const int col0 = bn * 128 + wc * 64;

  if constexpr (EPI == 0) {
    unsigned short* Cb = (unsigned short*)Cout + (long)bz * sC;
#pragma unroll
    for (int i = 0; i < 4; ++i)
#pragma unroll
      for (int j = 0; j < 4; ++j) {
        const int col = col0 + j * 16 + l15;
        const float bv = bias ? bias[col] : 0.0f;
#pragma unroll
        for (int r = 0; r < 4; ++r) {
          const int row = row0 + i * 16 + lk * 4 + r;
          Cb[(long)row * N + col] = f2b(acc[i][j][r] + bv);
        }
      }
  } else {
    float* Cb = (float*)Cout + (long)bz * sC;
    const float g = gptr[0];
#pragma unroll
    for (int i = 0; i < 4; ++i)
#pragma unroll
      for (int j = 0; j < 4; ++j) {
        const int col = col0 + j * 16 + l15;
        const float tl = tailor[bz * 1024 + col];
#pragma unroll
        for (int r = 0; r < 4; ++r) {
          const int row = row0 + i * 16 + lk * 4 + r;
          const long idx = ((long)bz * 2048 + row) * 1024 + col;
          Cb[(long)row * N + col] = xin[idx] + g * ((Vsum[bz * 2048 + row] + acc[i][j][r]) * tl);
        }
      }
  }
}

extern "C" void kernel_launch(void* const* d_in, const int* in_sizes, int n_in,
                              void* d_out, int out_size, void* d_ws, size_t ws_size,
                              hipStream_t stream) {
  (void)in_sizes; (void)n_in; (void)out_size;
  const float* x     = (const float*)d_in[0];
  const float* Wq    = (const float*)d_in[1];
  const float* bq    = (const float*)d_in[2];
  const float* Wk    = (const float*)d_in[3];
  const float* bk    = (const float*)d_in[4];
  const float* Wv    = (const float*)d_in[5];
  const float* bv    = (const float*)d_in[6];
  const float* gamma = (const float*)d_in[7];

  // B=16, C=2048, L=D=1024
  const long NE = 16L * 2048 * 1024;          // 33,554,432 elements
  const long BUF = NE * 2;                    // 67,108,864 bytes per bf16 tensor

  char* w = (char*)d_ws;
  unsigned short* Qh  = (unsigned short*)(w);            // later overlaid by S
  unsigned short* Kh  = (unsigned short*)(w + BUF);
  unsigned short* Vh  = (unsigned short*)(w + 2 * BUF);
  unsigned short* XQT = (unsigned short*)(w + 3 * BUF);  // xh, later overlaid by QT
  unsigned short* KnT = (unsigned short*)(w + 4 * BUF);
  unsigned short* S   = Qh;                              // 16 x 1024 x 1024 bf16 (33.5 MB)
  size_t off = 5 * (size_t)BUF;
  unsigned short* Wqh = (unsigned short*)(w + off); off += 2097152;
  unsigned short* Wkh = (unsigned short*)(w + off); off += 2097152;
  unsigned short* Wvh = (unsigned short*)(w + off); off += 2097152;
  float* pq     = (float*)(w + off); off += 1048576;
  float* pk     = (float*)(w + off); off += 1048576;
  float* tp     = (float*)(w + off); off += 1048576;
  float* invq   = (float*)(w + off); off += 65536;
  float* invk   = (float*)(w + off); off += 65536;
  float* tailor = (float*)(w + off); off += 65536;
  float* Ksum   = (float*)(w + off); off += 131072;
  float* Vsum   = (float*)(w + off); off += 131072;
  if (ws_size < off) return;  // workspace too small -> fail loudly at validation

  unsigned short* xh = XQT;

  // 1) casts
  k_f32_to_bf16<<<dim3((unsigned)(NE / 1024)), 256, 0, stream>>>(x, xh, NE);
  k_f32_to_bf16<<<dim3(1024), 256, 0, stream>>>(Wq, Wqh, 1048576);
  k_f32_to_bf16<<<dim3(1024), 256, 0, stream>>>(Wk, Wkh, 1048576);
  k_f32_to_bf16<<<dim3(1024), 256, 0, stream>>>(Wv, Wvh, 1048576);

  // 2) Q/K/V = x @ W^T + b   (M=32768, N=1024, K=1024; NT layout)
  dim3 g1(8, 256, 1);
  k_gemm_bt<0><<<g1, 256, 0, stream>>>(xh, Wqh, Qh, 1024, 1024, 0, 0, 0, bq,
                                       nullptr, nullptr, nullptr, nullptr);
  k_gemm_bt<0><<<g1, 256, 0, stream>>>(xh, Wkh, Kh, 1024, 1024, 0, 0, 0, bk,
                                       nullptr, nullptr, nullptr, nullptr);
  k_gemm_bt<0><<<g1, 256, 0, stream>>>(xh, Wvh, Vh, 1024, 1024, 0, 0, 0, bv,
                                       nullptr, nullptr, nullptr, nullptr);

  // 3) column L2 norms of Q,K over C
  k_norms_part<<<dim3(16, 16), 256, 0, stream>>>(Qh, Kh, pq, pk);
  k_norms_fin<<<dim3(64), 256, 0, stream>>>(pq, pk, invq, invk);

  // 4) Ksum (with invk), Vsum
  k_rowsums<<<dim3(8192), 256, 0, stream>>>(Kh, Vh, invk, Ksum, Vsum);

  // 5) tailor (reads Qh — must precede S overlay)
  k_tailor_part<<<dim3(16, 16), 256, 0, stream>>>(Qh, Ksum, tp);
  k_tailor_fin<<<dim3(64), 256, 0, stream>>>(tp, invq, tailor);

  // 6) QT[n][c] = Q[c][n]*invq[n]  (overlays xh; QKV GEMMs done)
  k_transpose_scale<<<dim3(32, 16, 16), 256, 0, stream>>>(Qh, invq, XQT);

  // 7) KnT[l][c] = K[c][l]*invk[l]
  k_transpose_scale<<<dim3(32, 16, 16), 256, 0, stream>>>(Kh, invk, KnT);

  // 8) S[p][l] = sum_m QT[p][m]*KnT[l][m]  (per batch, M=N=1024, K=2048) — overlays Qh
  k_gemm_bt<0><<<dim3(8, 8, 16), 256, 0, stream>>>(
      XQT, KnT, S, 1024, 2048, 1024L * 2048, 1024L * 2048, 1024L * 1024, nullptr,
      nullptr, nullptr, nullptr, nullptr);

  // 9) out[c][n] = x + gamma*(Vsum[c] + sum_l V[c][l]*S[n][l]) * tailor[n]
  k_gemm_bt<1><<<dim3(8, 16, 16), 256, 0, stream>>>(
      Vh, S, d_out, 1024, 1024, 2048L * 1024, 1024L * 1024, 2048L * 1024, nullptr,
      x, Vsum, tailor, gamma);
}

// Round 3
// 692.427 us; speedup vs baseline: 1.3480x; 1.0741x over previous
//
#include <hip/hip_runtime.h>
#include <cstdint>

#define DEV static __device__ __forceinline__

typedef __attribute__((ext_vector_type(8))) short short8v;     // 8 x bf16 bits
typedef __attribute__((ext_vector_type(4))) float f32x4;
typedef __attribute__((ext_vector_type(4))) float fl4;
typedef __attribute__((ext_vector_type(4))) unsigned short us4;
typedef __attribute__((ext_vector_type(8))) unsigned short us8;

DEV float b2f(unsigned short u) {
  union { unsigned int i; float f; } c; c.i = ((unsigned int)u) << 16; return c.f;
}
DEV unsigned short f2b(float f) {   // RNE float -> bf16 bits
  union { float f; unsigned int i; } c; c.f = f;
  unsigned int u = c.i;
  u += 0x7fffu + ((u >> 16) & 1u);
  return (unsigned short)(u >> 16);
}

DEV void gload16(const void* g, void* l) {  // async global->LDS, 16B/lane
  __builtin_amdgcn_global_load_lds(
      (const __attribute__((address_space(1))) unsigned int*)g,
      (__attribute__((address_space(3))) unsigned int*)l, 16, 0, 0);
}

DEV float red16(float v) {  // reduce across the 16 lanes sharing lk (xor in low 4 bits)
  v += __shfl_xor(v, 1); v += __shfl_xor(v, 2);
  v += __shfl_xor(v, 4); v += __shfl_xor(v, 8);
  return v;
}
DEV float red4lk(float v) { // reduce across the 4 lk groups (xor bits 4,5)
  v += __shfl_xor(v, 16); v += __shfl_xor(v, 32);
  return v;
}

// ---------------- elementwise f32 -> bf16 ----------------
__global__ __launch_bounds__(256) void k_f32_to_bf16(const float* __restrict__ src,
                                                     unsigned short* __restrict__ dst, long n) {
  long i = ((long)blockIdx.x * 256 + threadIdx.x) * 4;
  if (i >= n) return;
  fl4 v = *(const fl4*)(src + i);
  us4 o;
  o[0] = f2b(v[0]); o[1] = f2b(v[1]); o[2] = f2b(v[2]); o[3] = f2b(v[3]);
  *(us4*)(dst + i) = o;
}

// ---------------- finalize inverse norms ----------------
__global__ __launch_bounds__(256) void k_norms_fin(const float* __restrict__ pq,
                                                   const float* __restrict__ pk,
                                                   float* __restrict__ invq, float* __restrict__ invk) {
  const int gid = blockIdx.x * 256 + threadIdx.x;   // 16384
  invq[gid] = rsqrtf(pq[gid]);
  invk[gid] = rsqrtf(pk[gid]);
}

// ---------------- finalize tailor: 1/(L + rowsum(S) + eps*invq*colsum(Q)) ----------------
__global__ __launch_bounds__(256) void k_tailor_fin(const float* __restrict__ Srow,
                                                    const float* __restrict__ invq,
                                                    const float* __restrict__ qsum,
                                                    float* __restrict__ tailor) {
  const int gid = blockIdx.x * 256 + threadIdx.x;   // 16384
  tailor[gid] = 1.0f / (1024.0f + Srow[gid] + 1e-6f * invq[gid] * qsum[gid]);
}

// ---------------- transpose+scale: (B,C=2048,L=1024) -> (B,L,C), dst row j scaled by s[b*1024+j] ----------------
__global__ __launch_bounds__(256) void k_transpose_scale(const unsigned short* __restrict__ Q,
                                                         const float* __restrict__ scale,
                                                         unsigned short* __restrict__ QT) {
  __shared__ unsigned short tile[64][68];
  const int c0 = blockIdx.x * 64, n0 = blockIdx.y * 64, b = blockIdx.z;
  const int jr = (threadIdx.x & 15) * 4;
  const int ir = threadIdx.x >> 4;
  const unsigned short* src = Q + ((long)b * 2048 + c0) * 1024 + n0;
#pragma unroll
  for (int p = 0; p < 4; ++p) {
    int i = ir + p * 16;
    *(us4*)&tile[i][jr] = *(const us4*)(src + (long)i * 1024 + jr);
  }
  __syncthreads();
  unsigned short* dst = QT + ((long)b * 1024 + n0) * 2048 + c0;
#pragma unroll
  for (int p = 0; p < 4; ++p) {
    int j = ir + p * 16;
    const float s = scale[b * 1024 + n0 + j];
    us4 o;
    o[0] = f2b(b2f(tile[jr + 0][j]) * s);
    o[1] = f2b(b2f(tile[jr + 1][j]) * s);
    o[2] = f2b(b2f(tile[jr + 2][j]) * s);
    o[3] = f2b(b2f(tile[jr + 3][j]) * s);
    *(us4*)(dst + (long)j * 2048 + jr) = o;
  }
}

// ---------------- NT GEMM: C[m][n] = sum_k A[m][k] * Bt[n][k]  (both K-contiguous) ----------------
// 128x128 tile, BK=32, 4 waves (2x2), each wave 64x64 via 4x4 MFMA 16x16x32 bf16.
// EPI 1: fused final fp32 epilogue (residual from bf16 xh).
// EPI 2: bf16 out + bias + per-col atomic sum-of-squares (acc1).   [K]
// EPI 3: bf16 out + bias + per-col atomic sumsq (acc1) + sum (acc2). [Q]
// EPI 4: bf16 out + optional bias + per-row atomic sum (acc1, indexed bz*accStride+row). [V, S]
template<int EPI>
__global__ __launch_bounds__(256)
void k_gemm_bt(const unsigned short* __restrict__ A,
               const unsigned short* __restrict__ Bt,
               void* __restrict__ Cout,
               int N, int K,
               long sA, long sB, long sC,
               const float* __restrict__ bias,
               float* __restrict__ acc1,
               float* __restrict__ acc2,
               long accStride,
               const unsigned short* __restrict__ xh,
               const float* __restrict__ Vsum,
               const float* __restrict__ tailor,
               const float* __restrict__ gptr) {
  __shared__ __align__(16) unsigned short As[128 * 32];
  __shared__ __align__(16) unsigned short Bs[128 * 32];

  const int tid = threadIdx.x;
  const int wid = tid >> 6, lane = tid & 63;
  const int wr = wid >> 1, wc = wid & 1;
  const int l15 = lane & 15, lk = lane >> 4;

  // XCD-bijective swizzle over (x,y); nwg % 8 == 0 for all our grids
  const int nx = gridDim.x;
  const int nwg = nx * gridDim.y;
  const int lin = blockIdx.y * nx + blockIdx.x;
  const int cpx = nwg >> 3;
  const int wg = (lin & 7) * cpx + (lin >> 3);
  const int bn = wg % nx;
  const int bm = wg / nx;
  const int bz = blockIdx.z;

  const unsigned short* Ab = A + (long)bz * sA + (long)bm * 128 * K;
  const unsigned short* Bb = Bt + (long)bz * sB + (long)bn * 128 * K;

  const long soff = (long)(wid * 16 + (lane >> 2)) * K + (long)(lane & 3) * 8;

  f32x4 acc[4][4];
#pragma unroll
  for (int i = 0; i < 4; ++i)
#pragma unroll
    for (int j = 0; j < 4; ++j) acc[i][j] = (f32x4){0.f, 0.f, 0.f, 0.f};

  for (int k0 = 0; k0 < K; k0 += 32) {
    __syncthreads();
    gload16(Ab + soff + k0,                 As + wid * 512);
    gload16(Ab + soff + 64 * (long)K + k0,  As + 2048 + wid * 512);
    gload16(Bb + soff + k0,                 Bs + wid * 512);
    gload16(Bb + soff + 64 * (long)K + k0,  Bs + 2048 + wid * 512);
    __syncthreads();

    short8v af[4], bfr[4];
#pragma unroll
    for (int i = 0; i < 4; ++i)
      af[i] = *(const short8v*)(As + (wr * 64 + i * 16 + l15) * 32 + lk * 8);
#pragma unroll
    for (int j = 0; j < 4; ++j)
      bfr[j] = *(const short8v*)(Bs + (wc * 64 + j * 16 + l15) * 32 + lk * 8);
#pragma unroll
    for (int i = 0; i < 4; ++i)
#pragma unroll
      for (int j = 0; j < 4; ++j)
        acc[i][j] = __builtin_amdgcn_mfma_f32_16x16x32_bf16(af[i], bfr[j], acc[i][j], 0, 0, 0);
  }

  const int row0 = bm * 128 + wr * 64;
  const int col0 = bn * 128 + wc * 64;

  if constexpr (EPI == 1) {
    float* Cb = (float*)Cout + (long)bz * sC;
    const float g = gptr[0];
#pragma unroll
    for (int i = 0; i < 4; ++i)
#pragma unroll
      for (int j = 0; j < 4; ++j) {
        const int col = col0 + j * 16 + l15;
        const float tl = tailor[bz * 1024 + col];
#pragma unroll
        for (int r = 0; r < 4; ++r) {
          const int row = row0 + i * 16 + lk * 4 + r;
          const long idx = ((long)bz * 2048 + row) * 1024 + col;
          Cb[(long)row * N + col] = b2f(xh[idx]) + g * ((Vsum[bz * 2048 + row] + acc[i][j][r]) * tl);
        }
      }
  } else {
    unsigned short* Cb = (unsigned short*)Cout + (long)bz * sC;
    float bvj[4];
#pragma unroll
    for (int j = 0; j < 4; ++j) bvj[j] = bias ? bias[col0 + j * 16 + l15] : 0.0f;
#pragma unroll
    for (int i = 0; i < 4; ++i)
#pragma unroll
      for (int j = 0; j < 4; ++j) {
        const int col = col0 + j * 16 + l15;
#pragma unroll
        for (int r = 0; r < 4; ++r) {
          const int row = row0 + i * 16 + lk * 4 + r;
          Cb[(long)row * N + col] = f2b(acc[i][j][r] + bvj[j]);
        }
      }

    if constexpr (EPI == 2 || EPI == 3) {
      // per-column sum of squares (and sum) over this block's 128 rows
      const int b = bm >> 4;   // 16 m-blocks per batch (2048/128)
#pragma unroll
      for (int j = 0; j < 4; ++j) {
        const int col = col0 + j * 16 + l15;
        float ss = 0.f, sm = 0.f;
#pragma unroll
        for (int i = 0; i < 4; ++i)
#pragma unroll
          for (int r = 0; r < 4; ++r) {
            const float v = acc[i][j][r] + bvj[j];
            ss += v * v;
            if constexpr (EPI == 3) sm += v;
          }
        ss = red4lk(ss);
        if constexpr (EPI == 3) sm = red4lk(sm);
        if (lk == 0) {
          atomicAdd(&acc1[(long)b * 1024 + col], ss);
          if constexpr (EPI == 3) atomicAdd(&acc2[(long)b * 1024 + col], sm);
        }
      }
    }
    if constexpr (EPI == 4) {
      // per-row sum over this block's 128 cols
#pragma unroll
      for (int i = 0; i < 4; ++i)
#pragma unroll
        for (int r = 0; r < 4; ++r) {
          float sm = 0.f;
#pragma unroll
          for (int j = 0; j < 4; ++j) sm += acc[i][j][r] + bvj[j];
          sm = red16(sm);
          if (l15 == 0) {
            const int row = row0 + i * 16 + lk * 4 + r;
            atomicAdd(&acc1[(long)bz * accStride + row], sm);
          }
        }
    }
  }
}

extern "C" void kernel_launch(void* const* d_in, const int* in_sizes, int n_in,
                              void* d_out, int out_size, void* d_ws, size_t ws_size,
                              hipStream_t stream) {
  (void)in_sizes; (void)n_in; (void)out_size;
  const float* x     = (const float*)d_in[0];
  const float* Wq    = (const float*)d_in[1];
  const float* bq    = (const float*)d_in[2];
  const float* Wk    = (const float*)d_in[3];
  const float* bk    = (const float*)d_in[4];
  const float* Wv    = (const float*)d_in[5];
  const float* bv    = (const float*)d_in[6];
  const float* gamma = (const float*)d_in[7];

  // B=16, C=2048, L=D=1024
  const long NE = 16L * 2048 * 1024;          // 33,554,432 elements
  const long BUF = NE * 2;                    // 67,108,864 bytes per bf16 tensor

  char* w = (char*)d_ws;
  unsigned short* Qh  = (unsigned short*)(w);            // later overlaid by S
  unsigned short* Kh  = (unsigned short*)(w + BUF);      // later overlaid by QT
  unsigned short* Vh  = (unsigned short*)(w + 2 * BUF);
  unsigned short* xh  = (unsigned short*)(w + 3 * BUF);  // stays live to the end
  unsigned short* KnT = (unsigned short*)(w + 4 * BUF);
  unsigned short* S   = Qh;                              // 16 x 1024 x 1024 bf16 (33.5 MB)
  unsigned short* QT  = Kh;                              // 16 x 1024 x 2048 bf16
  size_t off = 5 * (size_t)BUF;
  unsigned short* Wqh = (unsigned short*)(w + off); off += 2097152;
  unsigned short* Wkh = (unsigned short*)(w + off); off += 2097152;
  unsigned short* Wvh = (unsigned short*)(w + off); off += 2097152;
  // zero-init accumulator block (one memset covers all of these)
  char* accbase = w + off;
  float* pq     = (float*)(w + off); off += 65536;       // col sumsq of Q  (16x1024)
  float* qsum   = (float*)(w + off); off += 65536;       // col sum of Q    (16x1024)
  float* pk     = (float*)(w + off); off += 65536;       // col sumsq of K  (16x1024)
  float* Vsum   = (float*)(w + off); off += 131072;      // row sum of V    (16x2048)
  float* Srow   = (float*)(w + off); off += 65536;       // row sum of S    (16x1024)
  const size_t accbytes = (size_t)(w + off - accbase);
  float* invq   = (float*)(w + off); off += 65536;
  float* invk   = (float*)(w + off); off += 65536;
  float* tailor = (float*)(w + off); off += 65536;
  if (ws_size < off) return;  // workspace too small -> fail loudly at validation

  // 0) zero the atomic accumulators (every call — deterministic)
  hipMemsetAsync(accbase, 0, accbytes, stream);

  // 1) casts
  k_f32_to_bf16<<<dim3((unsigned)(NE / 1024)), 256, 0, stream>>>(x, xh, NE);
  k_f32_to_bf16<<<dim3(1024), 256, 0, stream>>>(Wq, Wqh, 1048576);
  k_f32_to_bf16<<<dim3(1024), 256, 0, stream>>>(Wk, Wkh, 1048576);
  k_f32_to_bf16<<<dim3(1024), 256, 0, stream>>>(Wv, Wvh, 1048576);

  // 2) Q/K/V = x @ W^T + b   (M=32768, N=1024, K=1024; NT layout) with fused reductions
  dim3 g1(8, 256, 1);
  k_gemm_bt<3><<<g1, 256, 0, stream>>>(xh, Wqh, Qh, 1024, 1024, 0, 0, 0, bq,
                                       pq, qsum, 0, nullptr, nullptr, nullptr, nullptr);
  k_gemm_bt<2><<<g1, 256, 0, stream>>>(xh, Wkh, Kh, 1024, 1024, 0, 0, 0, bk,
                                       pk, nullptr, 0, nullptr, nullptr, nullptr, nullptr);
  k_gemm_bt<4><<<g1, 256, 0, stream>>>(xh, Wvh, Vh, 1024, 1024, 0, 0, 0, bv,
                                       Vsum, nullptr, 0, nullptr, nullptr, nullptr, nullptr);

  // 3) inverse norms
  k_norms_fin<<<dim3(64), 256, 0, stream>>>(pq, pk, invq, invk);

  // 4) KnT[l][c] = K[c][l]*invk[l]  (must precede QT overlay of Kh)
  k_transpose_scale<<<dim3(32, 16, 16), 256, 0, stream>>>(Kh, invk, KnT);

  // 5) QT[n][c] = Q[c][n]*invq[n]  (overlays Kh)
  k_transpose_scale<<<dim3(32, 16, 16), 256, 0, stream>>>(Qh, invq, QT);

  // 6) S[p][l] = sum_m QT[p][m]*KnT[l][m]  (per batch, M=N=1024, K=2048) — overlays Qh
  //    + fused per-row sums into Srow
  k_gemm_bt<4><<<dim3(8, 8, 16), 256, 0, stream>>>(
      QT, KnT, S, 1024, 2048, 1024L * 2048, 1024L * 2048, 1024L * 1024, nullptr,
      Srow, nullptr, 1024, nullptr, nullptr, nullptr, nullptr);

  // 7) tailor[n] = 1/(1024 + rowsum(S)[n] + eps*invq[n]*qsum[n])
  k_tailor_fin<<<dim3(64), 256, 0, stream>>>(Srow, invq, qsum, tailor);

  // 8) out[c][n] = xh + gamma*(Vsum[c] + sum_l V[c][l]*S[n][l]) * tailor[n]
  k_gemm_bt<1><<<dim3(8, 16, 16), 256, 0, stream>>>(
      Vh, S, d_out, 1024, 1024, 2048L * 1024, 1024L * 1024, 2048L * 1024, nullptr,
      nullptr, nullptr, 0, xh, Vsum, tailor, gamma);
}

// Round 4
// 647.720 us; speedup vs baseline: 1.4411x; 1.0690x over previous
//
#include <hip/hip_runtime.h>
#include <cstdint>

#define DEV static __device__ __forceinline__

typedef __attribute__((ext_vector_type(8))) short short8v;     // 8 x bf16 bits
typedef __attribute__((ext_vector_type(4))) float f32x4;
typedef __attribute__((ext_vector_type(4))) float fl4;
typedef __attribute__((ext_vector_type(4))) unsigned short us4;
typedef __attribute__((ext_vector_type(8))) unsigned short us8;

DEV float b2f(unsigned short u) {
  union { unsigned int i; float f; } c; c.i = ((unsigned int)u) << 16; return c.f;
}
DEV unsigned short f2b(float f) {   // RNE float -> bf16 bits
  union { float f; unsigned int i; } c; c.f = f;
  unsigned int u = c.i;
  u += 0x7fffu + ((u >> 16) & 1u);
  return (unsigned short)(u >> 16);
}

DEV void gload16(const void* g, void* l) {  // async global->LDS, 16B/lane
  __builtin_amdgcn_global_load_lds(
      (const __attribute__((address_space(1))) unsigned int*)g,
      (__attribute__((address_space(3))) unsigned int*)l, 16, 0, 0);
}

DEV float red16(float v) {  // reduce across 16 lanes sharing lk (xor low 4 bits)
  v += __shfl_xor(v, 1); v += __shfl_xor(v, 2);
  v += __shfl_xor(v, 4); v += __shfl_xor(v, 8);
  return v;
}
DEV float red4lk(float v) { // reduce across the 4 lk groups (xor bits 4,5)
  v += __shfl_xor(v, 16); v += __shfl_xor(v, 32);
  return v;
}

// ---------------- elementwise f32 -> bf16 ----------------
__global__ __launch_bounds__(256) void k_f32_to_bf16(const float* __restrict__ src,
                                                     unsigned short* __restrict__ dst, long n) {
  long i = ((long)blockIdx.x * 256 + threadIdx.x) * 4;
  if (i >= n) return;
  fl4 v = *(const fl4*)(src + i);
  us4 o;
  o[0] = f2b(v[0]); o[1] = f2b(v[1]); o[2] = f2b(v[2]); o[3] = f2b(v[3]);
  *(us4*)(dst + i) = o;
}

// ---------------- concat biases into 3072-float buffer ----------------
__global__ __launch_bounds__(256) void k_bias_cat(const float* __restrict__ bq,
                                                  const float* __restrict__ bk,
                                                  const float* __restrict__ bv,
                                                  float* __restrict__ o) {
  const int t = blockIdx.x * 256 + threadIdx.x;   // 3072
  o[t] = t < 1024 ? bq[t] : (t < 2048 ? bk[t - 1024] : bv[t - 2048]);
}

// ---------------- finalize inverse norms ----------------
__global__ __launch_bounds__(256) void k_norms_fin(const float* __restrict__ pq,
                                                   const float* __restrict__ pk,
                                                   float* __restrict__ invq, float* __restrict__ invk) {
  const int gid = blockIdx.x * 256 + threadIdx.x;   // 16384
  invq[gid] = rsqrtf(pq[gid]);
  invk[gid] = rsqrtf(pk[gid]);
}

// ---------------- finalize tailor: 1/(L + rowsum(S) + eps*invq*colsum(Q)) ----------------
__global__ __launch_bounds__(256) void k_tailor_fin(const float* __restrict__ Srow,
                                                    const float* __restrict__ invq,
                                                    const float* __restrict__ qsum,
                                                    float* __restrict__ tailor) {
  const int gid = blockIdx.x * 256 + threadIdx.x;   // 16384
  tailor[gid] = 1.0f / (1024.0f + Srow[gid] + 1e-6f * invq[gid] * qsum[gid]);
}

// ---------------- transpose+scale: (B,2048,1024) -> (B,1024,2048), dst row j scaled ----------------
__global__ __launch_bounds__(256) void k_transpose_scale(const unsigned short* __restrict__ Q,
                                                         const float* __restrict__ scale,
                                                         unsigned short* __restrict__ QT) {
  __shared__ unsigned short tile[64][68];
  const int c0 = blockIdx.x * 64, n0 = blockIdx.y * 64, b = blockIdx.z;
  const int jr = (threadIdx.x & 15) * 4;
  const int ir = threadIdx.x >> 4;
  const unsigned short* src = Q + ((long)b * 2048 + c0) * 1024 + n0;
#pragma unroll
  for (int p = 0; p < 4; ++p) {
    int i = ir + p * 16;
    *(us4*)&tile[i][jr] = *(const us4*)(src + (long)i * 1024 + jr);
  }
  __syncthreads();
  unsigned short* dst = QT + ((long)b * 1024 + n0) * 2048 + c0;
#pragma unroll
  for (int p = 0; p < 4; ++p) {
    int j = ir + p * 16;
    const float s = scale[b * 1024 + n0 + j];
    us4 o;
    o[0] = f2b(b2f(tile[jr + 0][j]) * s);
    o[1] = f2b(b2f(tile[jr + 1][j]) * s);
    o[2] = f2b(b2f(tile[jr + 2][j]) * s);
    o[3] = f2b(b2f(tile[jr + 3][j]) * s);
    *(us4*)(dst + (long)j * 2048 + jr) = o;
  }
}

// ---------------- 256x256 NT GEMM, BK=32, 8 waves (2Mx4N), dbuf LDS + counted vmcnt ----------
// C[m][n] = sum_k A[m][k] * Bt[n][k]; out col-stride fixed 1024.
// EPI 1: final fused fp32 epilogue (residual bf16 xh, Vsum, tailor, gamma).
// EPI 4: bf16 out + per-row atomic sum into r4[bz*1024+row].                  [S]
// EPI 5: merged QKV: out segment by col (Q/K/V), bias, fused reductions.
template<int EPI>
__global__ __launch_bounds__(512)
void k_g256(const unsigned short* __restrict__ A,
            const unsigned short* __restrict__ Bt,
            void* __restrict__ O0, void* __restrict__ O1, void* __restrict__ O2,
            int K, long sA, long sB, long sC,
            const float* __restrict__ bias,
            float* __restrict__ r1, float* __restrict__ r2,
            float* __restrict__ r3, float* __restrict__ r4,
            const unsigned short* __restrict__ xh,
            const float* __restrict__ Vsum,
            const float* __restrict__ tailor,
            const float* __restrict__ gptr) {
  __shared__ __align__(16) unsigned short As[2][8192];   // 2 x 256x32 bf16 = 32 KiB
  __shared__ __align__(16) unsigned short Bs[2][8192];   // 32 KiB   (total 64 KiB)

  const int tid = threadIdx.x;
  const int wv = tid >> 6, lane = tid & 63;
  const int wr = wv >> 2, wcn = wv & 3;          // 2 x 4 wave grid
  const int l15 = lane & 15, lk = lane >> 4;

  // XCD-bijective swizzle over (x,y); nwg % 8 == 0 for all grids used
  const int nx = gridDim.x;
  const int nwg = nx * gridDim.y;
  const int lin = blockIdx.y * nx + blockIdx.x;
  const int cpx = nwg >> 3;
  const int wg = (lin & 7) * cpx + (lin >> 3);
  const int bn = wg % nx;
  const int bm = wg / nx;
  const int bz = blockIdx.z;

  const unsigned short* Ab = A + (long)bz * sA + (long)bm * 256 * K;
  const unsigned short* Bb = Bt + (long)bz * sB + (long)bn * 256 * K;

  // staging: element e = q*4096 + tid*8  ->  row r = q*128 + (tid>>2), chunk c = tid&3
  const long soff = (long)(tid >> 2) * K + (long)(tid & 3) * 8;
  const int ldsoff = wv * 512;   // + q*4096, lane*8 added by HW

  f32x4 acc[8][4];
#pragma unroll
  for (int i = 0; i < 8; ++i)
#pragma unroll
    for (int j = 0; j < 4; ++j) acc[i][j] = (f32x4){0.f, 0.f, 0.f, 0.f};

  // prologue: stage tile 0 into buffer 0
#pragma unroll
  for (int q = 0; q < 2; ++q) {
    gload16(Ab + soff + q * (128L * K), &As[0][q * 4096 + ldsoff]);
    gload16(Bb + soff + q * (128L * K), &Bs[0][q * 4096 + ldsoff]);
  }

  const int nt = K >> 5;
  int cur = 0;
  for (int t = 0; t < nt; ++t) {
    if (t + 1 < nt) {
      const long kb = (long)(t + 1) * 32;
#pragma unroll
      for (int q = 0; q < 2; ++q) {
        gload16(Ab + soff + q * (128L * K) + kb, &As[cur ^ 1][q * 4096 + ldsoff]);
        gload16(Bb + soff + q * (128L * K) + kb, &Bs[cur ^ 1][q * 4096 + ldsoff]);
      }
      asm volatile("s_waitcnt vmcnt(4)" ::: "memory");   // tile t landed; t+1 stays in flight
    } else {
      asm volatile("s_waitcnt vmcnt(0)" ::: "memory");
    }
    __builtin_amdgcn_s_barrier();
    __builtin_amdgcn_sched_barrier(0);

    // B fragments: 4 x ds_read_b128
    short8v bfr[4];
#pragma unroll
    for (int j = 0; j < 4; ++j)
      bfr[j] = *(const short8v*)&Bs[cur][(wcn * 64 + j * 16 + l15) * 32 + lk * 8];

#pragma unroll
    for (int ih = 0; ih < 4; ++ih) {
      short8v af0 = *(const short8v*)&As[cur][(wr * 128 + (ih * 2 + 0) * 16 + l15) * 32 + lk * 8];
      short8v af1 = *(const short8v*)&As[cur][(wr * 128 + (ih * 2 + 1) * 16 + l15) * 32 + lk * 8];
      __builtin_amdgcn_s_setprio(1);
#pragma unroll
      for (int j = 0; j < 4; ++j) {
        acc[ih * 2 + 0][j] = __builtin_amdgcn_mfma_f32_16x16x32_bf16(af0, bfr[j], acc[ih * 2 + 0][j], 0, 0, 0);
        acc[ih * 2 + 1][j] = __builtin_amdgcn_mfma_f32_16x16x32_bf16(af1, bfr[j], acc[ih * 2 + 1][j], 0, 0, 0);
      }
      __builtin_amdgcn_s_setprio(0);
    }
    __builtin_amdgcn_sched_barrier(0);
    __builtin_amdgcn_s_barrier();
    cur ^= 1;
  }

  const int row0 = bm * 256 + wr * 128;
  const int col0 = bn * 256 + wcn * 64;

  if constexpr (EPI == 1) {
    float* Cb = (float*)O0 + (long)bz * sC;
    const float g = gptr[0];
#pragma unroll
    for (int i = 0; i < 8; ++i)
#pragma unroll
      for (int j = 0; j < 4; ++j) {
        const int col = col0 + j * 16 + l15;
        const float tl = tailor[bz * 1024 + col];
#pragma unroll
        for (int r = 0; r < 4; ++r) {
          const int row = row0 + i * 16 + lk * 4 + r;
          const long idx = ((long)bz * 2048 + row) * 1024 + col;
          Cb[(long)row * 1024 + col] = b2f(xh[idx]) + g * ((Vsum[bz * 2048 + row] + acc[i][j][r]) * tl);
        }
      }
  } else if constexpr (EPI == 4) {
    unsigned short* Cb = (unsigned short*)O0 + (long)bz * sC;
#pragma unroll
    for (int i = 0; i < 8; ++i) {
#pragma unroll
      for (int j = 0; j < 4; ++j) {
        const int col = col0 + j * 16 + l15;
#pragma unroll
        for (int r = 0; r < 4; ++r) {
          const int row = row0 + i * 16 + lk * 4 + r;
          Cb[(long)row * 1024 + col] = f2b(acc[i][j][r]);
        }
      }
#pragma unroll
      for (int r = 0; r < 4; ++r) {
        float sm = acc[i][0][r] + acc[i][1][r] + acc[i][2][r] + acc[i][3][r];
        sm = red16(sm);
        if (l15 == 0) {
          const int row = row0 + i * 16 + lk * 4 + r;
          atomicAdd(&r4[(long)bz * 1024 + row], sm);
        }
      }
    }
  } else {  // EPI == 5: merged QKV
    const int seg = bn >> 2;             // 0=Q, 1=K, 2=V
    unsigned short* outp = seg == 0 ? (unsigned short*)O0
                        : seg == 1 ? (unsigned short*)O1 : (unsigned short*)O2;
    const int b = bm >> 3;               // batch (2048 rows per batch, 8 m-tiles)
    float bvj[4];
#pragma unroll
    for (int j = 0; j < 4; ++j) bvj[j] = bias[col0 + j * 16 + l15];
    const int colL0 = col0 & 1023;
#pragma unroll
    for (int i = 0; i < 8; ++i)
#pragma unroll
      for (int j = 0; j < 4; ++j) {
        const int colL = colL0 + j * 16 + l15;
#pragma unroll
        for (int r = 0; r < 4; ++r) {
          const int row = row0 + i * 16 + lk * 4 + r;
          outp[(long)row * 1024 + colL] = f2b(acc[i][j][r] + bvj[j]);
        }
      }
    if (seg < 2) {
      // per-column sumsq (and sum for Q) over this block's 256 rows
#pragma unroll
      for (int j = 0; j < 4; ++j) {
        const int colL = colL0 + j * 16 + l15;
        float ss = 0.f, sm = 0.f;
#pragma unroll
        for (int i = 0; i < 8; ++i)
#pragma unroll
          for (int r = 0; r < 4; ++r) {
            const float v = acc[i][j][r] + bvj[j];
            ss += v * v; sm += v;
          }
        ss = red4lk(ss);
        if (seg == 0) sm = red4lk(sm);
        if (lk == 0) {
          atomicAdd(&(seg == 0 ? r1 : r3)[(long)b * 1024 + colL], ss);
          if (seg == 0) atomicAdd(&r2[(long)b * 1024 + colL], sm);
        }
      }
    } else {
      // per-row sum over this block's 256 cols (V row-sums)
#pragma unroll
      for (int i = 0; i < 8; ++i)
#pragma unroll
        for (int r = 0; r < 4; ++r) {
          float sm = 0.f;
#pragma unroll
          for (int j = 0; j < 4; ++j) sm += acc[i][j][r] + bvj[j];
          sm = red16(sm);
          if (l15 == 0) {
            const int row = row0 + i * 16 + lk * 4 + r;
            atomicAdd(&r4[row], sm);
          }
        }
    }
  }
}

extern "C" void kernel_launch(void* const* d_in, const int* in_sizes, int n_in,
                              void* d_out, int out_size, void* d_ws, size_t ws_size,
                              hipStream_t stream) {
  (void)in_sizes; (void)n_in; (void)out_size;
  const float* x     = (const float*)d_in[0];
  const float* Wq    = (const float*)d_in[1];
  const float* bq    = (const float*)d_in[2];
  const float* Wk    = (const float*)d_in[3];
  const float* bk    = (const float*)d_in[4];
  const float* Wv    = (const float*)d_in[5];
  const float* bv    = (const float*)d_in[6];
  const float* gamma = (const float*)d_in[7];

  // B=16, C=2048, L=D=1024
  const long NE = 16L * 2048 * 1024;
  const long BUF = NE * 2;                    // bytes per bf16 tensor

  char* w = (char*)d_ws;
  unsigned short* Qh  = (unsigned short*)(w);            // later overlaid by S
  unsigned short* Kh  = (unsigned short*)(w + BUF);      // later overlaid by QT
  unsigned short* Vh  = (unsigned short*)(w + 2 * BUF);
  unsigned short* xh  = (unsigned short*)(w + 3 * BUF);  // live to the end
  unsigned short* KnT = (unsigned short*)(w + 4 * BUF);
  unsigned short* S   = Qh;
  unsigned short* QT  = Kh;
  size_t off = 5 * (size_t)BUF;
  unsigned short* Wqkvh = (unsigned short*)(w + off); off += 3 * 2097152;  // Wq|Wk|Wv contiguous
  char* accbase = w + off;
  float* pq     = (float*)(w + off); off += 65536;       // col sumsq of Q  (16x1024)
  float* qsum   = (float*)(w + off); off += 65536;       // col sum of Q
  float* pk     = (float*)(w + off); off += 65536;       // col sumsq of K
  float* Vsum   = (float*)(w + off); off += 131072;      // row sum of V    (16x2048)
  float* Srow   = (float*)(w + off); off += 65536;       // row sum of S    (16x1024)
  const size_t accbytes = (size_t)(w + off - accbase);
  float* invq   = (float*)(w + off); off += 65536;
  float* invk   = (float*)(w + off); off += 65536;
  float* tailor = (float*)(w + off); off += 65536;
  float* bqkv   = (float*)(w + off); off += 12288;
  if (ws_size < off) return;

  // 0) zero atomic accumulators
  hipMemsetAsync(accbase, 0, accbytes, stream);

  // 1) casts + bias concat
  k_f32_to_bf16<<<dim3((unsigned)(NE / 1024)), 256, 0, stream>>>(x, xh, NE);
  k_f32_to_bf16<<<dim3(1024), 256, 0, stream>>>(Wq, Wqkvh, 1048576);
  k_f32_to_bf16<<<dim3(1024), 256, 0, stream>>>(Wk, Wqkvh + 1048576, 1048576);
  k_f32_to_bf16<<<dim3(1024), 256, 0, stream>>>(Wv, Wqkvh + 2097152, 1048576);
  k_bias_cat<<<dim3(12), 256, 0, stream>>>(bq, bk, bv, bqkv);

  // 2) merged QKV GEMM: M=32768, N=3072, K=1024 + fused reductions
  k_g256<5><<<dim3(12, 128, 1), 512, 0, stream>>>(
      xh, Wqkvh, Qh, Kh, Vh, 1024, 0, 0, 0, bqkv,
      pq, qsum, pk, Vsum, nullptr, nullptr, nullptr, nullptr);

  // 3) inverse norms
  k_norms_fin<<<dim3(64), 256, 0, stream>>>(pq, pk, invq, invk);

  // 4) KnT = T(Kh)*invk   (before QT overlays Kh)
  k_transpose_scale<<<dim3(32, 16, 16), 256, 0, stream>>>(Kh, invk, KnT);

  // 5) QT = T(Qh)*invq    (overlays Kh)
  k_transpose_scale<<<dim3(32, 16, 16), 256, 0, stream>>>(Qh, invq, QT);

  // 6) S = QT x KnT^T per batch (M=N=1024, K=2048) + row sums — overlays Qh
  k_g256<4><<<dim3(4, 4, 16), 512, 0, stream>>>(
      QT, KnT, S, nullptr, nullptr, 2048, 1024L * 2048, 1024L * 2048, 1024L * 1024,
      nullptr, nullptr, nullptr, nullptr, Srow, nullptr, nullptr, nullptr, nullptr);

  // 7) tailor
  k_tailor_fin<<<dim3(64), 256, 0, stream>>>(Srow, invq, qsum, tailor);

  // 8) out = xh + gamma*(Vsum + V x S^T) * tailor   (M=2048/batch, N=1024, K=1024)
  k_g256<1><<<dim3(4, 8, 16), 512, 0, stream>>>(
      Vh, S, d_out, nullptr, nullptr, 1024, 2048L * 1024, 1024L * 1024, 2048L * 1024,
      nullptr, nullptr, nullptr, nullptr, nullptr, xh, Vsum, tailor, gamma);
}

// Round 5
// 633.223 us; speedup vs baseline: 1.4740x; 1.0229x over previous
//
#include <hip/hip_runtime.h>
#include <cstdint>

#define DEV static __device__ __forceinline__

typedef __attribute__((ext_vector_type(8))) short short8v;     // 8 x bf16 bits
typedef __attribute__((ext_vector_type(4))) float f32x4;
typedef __attribute__((ext_vector_type(4))) float fl4;
typedef __attribute__((ext_vector_type(4))) unsigned short us4;
typedef __attribute__((ext_vector_type(8))) unsigned short us8;

DEV float b2f(unsigned short u) {
  union { unsigned int i; float f; } c; c.i = ((unsigned int)u) << 16; return c.f;
}
DEV unsigned short f2b(float f) {   // RNE float -> bf16 bits
  union { float f; unsigned int i; } c; c.f = f;
  unsigned int u = c.i;
  u += 0x7fffu + ((u >> 16) & 1u);
  return (unsigned short)(u >> 16);
}

DEV void gload16(const void* g, void* l) {  // async global->LDS, 16B/lane
  __builtin_amdgcn_global_load_lds(
      (const __attribute__((address_space(1))) unsigned int*)g,
      (__attribute__((address_space(3))) unsigned int*)l, 16, 0, 0);
}

DEV float red16(float v) {  // reduce across 16 lanes sharing lk (xor low 4 bits)
  v += __shfl_xor(v, 1); v += __shfl_xor(v, 2);
  v += __shfl_xor(v, 4); v += __shfl_xor(v, 8);
  return v;
}
DEV float red4lk(float v) { // reduce across the 4 lk groups (xor bits 4,5)
  v += __shfl_xor(v, 16); v += __shfl_xor(v, 32);
  return v;
}

// ---------------- elementwise f32 -> bf16 ----------------
__global__ __launch_bounds__(256) void k_f32_to_bf16(const float* __restrict__ src,
                                                     unsigned short* __restrict__ dst, long n) {
  long i = ((long)blockIdx.x * 256 + threadIdx.x) * 4;
  if (i >= n) return;
  fl4 v = *(const fl4*)(src + i);
  us4 o;
  o[0] = f2b(v[0]); o[1] = f2b(v[1]); o[2] = f2b(v[2]); o[3] = f2b(v[3]);
  *(us4*)(dst + i) = o;
}

// ---------------- concat biases into 3072-float buffer ----------------
__global__ __launch_bounds__(256) void k_bias_cat(const float* __restrict__ bq,
                                                  const float* __restrict__ bk,
                                                  const float* __restrict__ bv,
                                                  float* __restrict__ o) {
  const int t = blockIdx.x * 256 + threadIdx.x;   // 3072
  o[t] = t < 1024 ? bq[t] : (t < 2048 ? bk[t - 1024] : bv[t - 2048]);
}

// ---------------- finalize inverse norms ----------------
__global__ __launch_bounds__(256) void k_norms_fin(const float* __restrict__ pq,
                                                   const float* __restrict__ pk,
                                                   float* __restrict__ invq, float* __restrict__ invk) {
  const int gid = blockIdx.x * 256 + threadIdx.x;   // 16384
  invq[gid] = rsqrtf(pq[gid]);
  invk[gid] = rsqrtf(pk[gid]);
}

// ---------------- finalize tailor: 1/(L + rowsum(S) + eps*invq*colsum(Q)) ----------------
__global__ __launch_bounds__(256) void k_tailor_fin(const float* __restrict__ Srow,
                                                    const float* __restrict__ invq,
                                                    const float* __restrict__ qsum,
                                                    float* __restrict__ tailor) {
  const int gid = blockIdx.x * 256 + threadIdx.x;   // 16384
  tailor[gid] = 1.0f / (1024.0f + Srow[gid] + 1e-6f * invq[gid] * qsum[gid]);
}

// ---------------- transpose+scale: (B,2048,1024) -> (B,1024,2048), dst row j scaled ----------------
__global__ __launch_bounds__(256) void k_transpose_scale(const unsigned short* __restrict__ Q,
                                                         const float* __restrict__ scale,
                                                         unsigned short* __restrict__ QT) {
  __shared__ unsigned short tile[64][68];
  const int c0 = blockIdx.x * 64, n0 = blockIdx.y * 64, b = blockIdx.z;
  const int jr = (threadIdx.x & 15) * 4;
  const int ir = threadIdx.x >> 4;
  const unsigned short* src = Q + ((long)b * 2048 + c0) * 1024 + n0;
#pragma unroll
  for (int p = 0; p < 4; ++p) {
    int i = ir + p * 16;
    *(us4*)&tile[i][jr] = *(const us4*)(src + (long)i * 1024 + jr);
  }
  __syncthreads();
  unsigned short* dst = QT + ((long)b * 1024 + n0) * 2048 + c0;
#pragma unroll
  for (int p = 0; p < 4; ++p) {
    int j = ir + p * 16;
    const float s = scale[b * 1024 + n0 + j];
    us4 o;
    o[0] = f2b(b2f(tile[jr + 0][j]) * s);
    o[1] = f2b(b2f(tile[jr + 1][j]) * s);
    o[2] = f2b(b2f(tile[jr + 2][j]) * s);
    o[3] = f2b(b2f(tile[jr + 3][j]) * s);
    *(us4*)(dst + (long)j * 2048 + jr) = o;
  }
}

// ---------------- 256x256 NT GEMM, BK=32, 8 waves (2Mx4N), dbuf LDS + counted vmcnt ----------
// LDS chunk-swizzle (T2, both-sides): logical (row, chunk c in [0,4)) stored at physical
// slot row*4 + (c ^ ((row>>1)&3)). Stage side achieves this by pre-swizzling the GLOBAL
// source chunk per lane (LDS dest stays linear, as global_load_lds requires); read side
// applies the same XOR. Spreads each lk-group's 16 lanes over all 8 bank-quads (2-way = free).
// C[m][n] = sum_k A[m][k] * Bt[n][k]; out col-stride fixed 1024.
// EPI 1: final fused fp32 epilogue (residual bf16 xh, Vsum, tailor, gamma).
// EPI 4: bf16 out + per-row atomic sum into r4[bz*1024+row].                  [S]
// EPI 5: merged QKV: out segment by col (Q/K/V), bias, fused reductions.
template<int EPI>
__global__ __launch_bounds__(512)
void k_g256(const unsigned short* __restrict__ A,
            const unsigned short* __restrict__ Bt,
            void* __restrict__ O0, void* __restrict__ O1, void* __restrict__ O2,
            int K, long sA, long sB, long sC,
            const float* __restrict__ bias,
            float* __restrict__ r1, float* __restrict__ r2,
            float* __restrict__ r3, float* __restrict__ r4,
            const unsigned short* __restrict__ xh,
            const float* __restrict__ Vsum,
            const float* __restrict__ tailor,
            const float* __restrict__ gptr) {
  __shared__ __align__(16) unsigned short As[2][8192];   // 2 x 256x32 bf16 = 32 KiB
  __shared__ __align__(16) unsigned short Bs[2][8192];   // 32 KiB   (total 64 KiB)

  const int tid = threadIdx.x;
  const int wv = tid >> 6, lane = tid & 63;
  const int wr = wv >> 2, wcn = wv & 3;          // 2 x 4 wave grid
  const int l15 = lane & 15, lk = lane >> 4;

  // XCD-bijective swizzle over (x,y); nwg % 8 == 0 for all grids used
  const int nx = gridDim.x;
  const int nwg = nx * gridDim.y;
  const int lin = blockIdx.y * nx + blockIdx.x;
  const int cpx = nwg >> 3;
  const int wg = (lin & 7) * cpx + (lin >> 3);
  const int bn = wg % nx;
  const int bm = wg / nx;
  const int bz = blockIdx.z;

  const unsigned short* Ab = A + (long)bz * sA + (long)bm * 256 * K;
  const unsigned short* Bb = Bt + (long)bz * sB + (long)bn * 256 * K;

  // staging: lane tid fills physical slot (q*512 + tid); its logical (row, chunk) is
  // row = q*128 + (tid>>2), chunk = (tid&3) ^ ((row>>1)&3) = (tid&3) ^ ((tid>>3)&3).
  const int scsw = (tid & 3) ^ ((tid >> 3) & 3);
  const long soff = (long)(tid >> 2) * K + (long)scsw * 8;
  const int ldsoff = wv * 512;   // elements; + q*4096; lane*16B added by HW

  // read-side swizzle: chunk' = lk ^ ((row>>1)&3); row bits 1-2 come from l15 only.
  const int rdsw = (lk ^ ((l15 >> 1) & 3)) * 8;
  const int aoff0 = (wr * 128 + l15) * 32 + rdsw;   // + i*512 per 16-row step
  const int boff0 = (wcn * 64 + l15) * 32 + rdsw;   // + j*512

  f32x4 acc[8][4];
#pragma unroll
  for (int i = 0; i < 8; ++i)
#pragma unroll
    for (int j = 0; j < 4; ++j) acc[i][j] = (f32x4){0.f, 0.f, 0.f, 0.f};

  // prologue: stage tile 0 into buffer 0
#pragma unroll
  for (int q = 0; q < 2; ++q) {
    gload16(Ab + soff + q * (128L * K), &As[0][q * 4096 + ldsoff]);
    gload16(Bb + soff + q * (128L * K), &Bs[0][q * 4096 + ldsoff]);
  }

  const int nt = K >> 5;
  int cur = 0;
  for (int t = 0; t < nt; ++t) {
    if (t + 1 < nt) {
      const long kb = (long)(t + 1) * 32;
#pragma unroll
      for (int q = 0; q < 2; ++q) {
        gload16(Ab + soff + q * (128L * K) + kb, &As[cur ^ 1][q * 4096 + ldsoff]);
        gload16(Bb + soff + q * (128L * K) + kb, &Bs[cur ^ 1][q * 4096 + ldsoff]);
      }
      asm volatile("s_waitcnt vmcnt(4)" ::: "memory");   // tile t landed; t+1 stays in flight
    } else {
      asm volatile("s_waitcnt vmcnt(0)" ::: "memory");
    }
    __builtin_amdgcn_s_barrier();
    __builtin_amdgcn_sched_barrier(0);

    // B fragments: 4 x ds_read_b128 (conflict-free via swizzle)
    short8v bfr[4];
#pragma unroll
    for (int j = 0; j < 4; ++j)
      bfr[j] = *(const short8v*)&Bs[cur][boff0 + j * 512];

#pragma unroll
    for (int ih = 0; ih < 4; ++ih) {
      short8v af0 = *(const short8v*)&As[cur][aoff0 + (ih * 2 + 0) * 512];
      short8v af1 = *(const short8v*)&As[cur][aoff0 + (ih * 2 + 1) * 512];
      __builtin_amdgcn_s_setprio(1);
#pragma unroll
      for (int j = 0; j < 4; ++j) {
        acc[ih * 2 + 0][j] = __builtin_amdgcn_mfma_f32_16x16x32_bf16(af0, bfr[j], acc[ih * 2 + 0][j], 0, 0, 0);
        acc[ih * 2 + 1][j] = __builtin_amdgcn_mfma_f32_16x16x32_bf16(af1, bfr[j], acc[ih * 2 + 1][j], 0, 0, 0);
      }
      __builtin_amdgcn_s_setprio(0);
    }
    __builtin_amdgcn_sched_barrier(0);
    __builtin_amdgcn_s_barrier();
    cur ^= 1;
  }

  const int row0 = bm * 256 + wr * 128;
  const int col0 = bn * 256 + wcn * 64;

  if constexpr (EPI == 1) {
    float* Cb = (float*)O0 + (long)bz * sC;
    const float g = gptr[0];
#pragma unroll
    for (int i = 0; i < 8; ++i)
#pragma unroll
      for (int j = 0; j < 4; ++j) {
        const int col = col0 + j * 16 + l15;
        const float tl = tailor[bz * 1024 + col];
#pragma unroll
        for (int r = 0; r < 4; ++r) {
          const int row = row0 + i * 16 + lk * 4 + r;
          const long idx = ((long)bz * 2048 + row) * 1024 + col;
          Cb[(long)row * 1024 + col] = b2f(xh[idx]) + g * ((Vsum[bz * 2048 + row] + acc[i][j][r]) * tl);
        }
      }
  } else if constexpr (EPI == 4) {
    unsigned short* Cb = (unsigned short*)O0 + (long)bz * sC;
#pragma unroll
    for (int i = 0; i < 8; ++i) {
#pragma unroll
      for (int j = 0; j < 4; ++j) {
        const int col = col0 + j * 16 + l15;
#pragma unroll
        for (int r = 0; r < 4; ++r) {
          const int row = row0 + i * 16 + lk * 4 + r;
          Cb[(long)row * 1024 + col] = f2b(acc[i][j][r]);
        }
      }
#pragma unroll
      for (int r = 0; r < 4; ++r) {
        float sm = acc[i][0][r] + acc[i][1][r] + acc[i][2][r] + acc[i][3][r];
        sm = red16(sm);
        if (l15 == 0) {
          const int row = row0 + i * 16 + lk * 4 + r;
          atomicAdd(&r4[(long)bz * 1024 + row], sm);
        }
      }
    }
  } else {  // EPI == 5: merged QKV
    const int seg = bn >> 2;             // 0=Q, 1=K, 2=V
    unsigned short* outp = seg == 0 ? (unsigned short*)O0
                        : seg == 1 ? (unsigned short*)O1 : (unsigned short*)O2;
    const int b = bm >> 3;               // batch (2048 rows per batch, 8 m-tiles)
    float bvj[4];
#pragma unroll
    for (int j = 0; j < 4; ++j) bvj[j] = bias[col0 + j * 16 + l15];
    const int colL0 = col0 & 1023;
#pragma unroll
    for (int i = 0; i < 8; ++i)
#pragma unroll
      for (int j = 0; j < 4; ++j) {
        const int colL = colL0 + j * 16 + l15;
#pragma unroll
        for (int r = 0; r < 4; ++r) {
          const int row = row0 + i * 16 + lk * 4 + r;
          outp[(long)row * 1024 + colL] = f2b(acc[i][j][r] + bvj[j]);
        }
      }
    if (seg < 2) {
      // per-column sumsq (and sum for Q) over this block's 256 rows
#pragma unroll
      for (int j = 0; j < 4; ++j) {
        const int colL = colL0 + j * 16 + l15;
        float ss = 0.f, sm = 0.f;
#pragma unroll
        for (int i = 0; i < 8; ++i)
#pragma unroll
          for (int r = 0; r < 4; ++r) {
            const float v = acc[i][j][r] + bvj[j];
            ss += v * v; sm += v;
          }
        ss = red4lk(ss);
        if (seg == 0) sm = red4lk(sm);
        if (lk == 0) {
          atomicAdd(&(seg == 0 ? r1 : r3)[(long)b * 1024 + colL], ss);
          if (seg == 0) atomicAdd(&r2[(long)b * 1024 + colL], sm);
        }
      }
    } else {
      // per-row sum over this block's 256 cols (V row-sums)
#pragma unroll
      for (int i = 0; i < 8; ++i)
#pragma unroll
        for (int r = 0; r < 4; ++r) {
          float sm = 0.f;
#pragma unroll
          for (int j = 0; j < 4; ++j) sm += acc[i][j][r] + bvj[j];
          sm = red16(sm);
          if (l15 == 0) {
            const int row = row0 + i * 16 + lk * 4 + r;
            atomicAdd(&r4[row], sm);
          }
        }
    }
  }
}

extern "C" void kernel_launch(void* const* d_in, const int* in_sizes, int n_in,
                              void* d_out, int out_size, void* d_ws, size_t ws_size,
                              hipStream_t stream) {
  (void)in_sizes; (void)n_in; (void)out_size;
  const float* x     = (const float*)d_in[0];
  const float* Wq    = (const float*)d_in[1];
  const float* bq    = (const float*)d_in[2];
  const float* Wk    = (const float*)d_in[3];
  const float* bk    = (const float*)d_in[4];
  const float* Wv    = (const float*)d_in[5];
  const float* bv    = (const float*)d_in[6];
  const float* gamma = (const float*)d_in[7];

  // B=16, C=2048, L=D=1024
  const long NE = 16L * 2048 * 1024;
  const long BUF = NE * 2;                    // bytes per bf16 tensor

  char* w = (char*)d_ws;
  unsigned short* Qh  = (unsigned short*)(w);            // later overlaid by S
  unsigned short* Kh  = (unsigned short*)(w + BUF);      // later overlaid by QT
  unsigned short* Vh  = (unsigned short*)(w + 2 * BUF);
  unsigned short* xh  = (unsigned short*)(w + 3 * BUF);  // live to the end
  unsigned short* KnT = (unsigned short*)(w + 4 * BUF);
  unsigned short* S   = Qh;
  unsigned short* QT  = Kh;
  size_t off = 5 * (size_t)BUF;
  unsigned short* Wqkvh = (unsigned short*)(w + off); off += 3 * 2097152;  // Wq|Wk|Wv contiguous
  char* accbase = w + off;
  float* pq     = (float*)(w + off); off += 65536;       // col sumsq of Q  (16x1024)
  float* qsum   = (float*)(w + off); off += 65536;       // col sum of Q
  float* pk     = (float*)(w + off); off += 65536;       // col sumsq of K
  float* Vsum   = (float*)(w + off); off += 131072;      // row sum of V    (16x2048)
  float* Srow   = (float*)(w + off); off += 65536;       // row sum of S    (16x1024)
  const size_t accbytes = (size_t)(w + off - accbase);
  float* invq   = (float*)(w + off); off += 65536;
  float* invk   = (float*)(w + off); off += 65536;
  float* tailor = (float*)(w + off); off += 65536;
  float* bqkv   = (float*)(w + off); off += 12288;
  if (ws_size < off) return;

  // 0) zero atomic accumulators
  hipMemsetAsync(accbase, 0, accbytes, stream);

  // 1) casts + bias concat
  k_f32_to_bf16<<<dim3((unsigned)(NE / 1024)), 256, 0, stream>>>(x, xh, NE);
  k_f32_to_bf16<<<dim3(1024), 256, 0, stream>>>(Wq, Wqkvh, 1048576);
  k_f32_to_bf16<<<dim3(1024), 256, 0, stream>>>(Wk, Wqkvh + 1048576, 1048576);
  k_f32_to_bf16<<<dim3(1024), 256, 0, stream>>>(Wv, Wqkvh + 2097152, 1048576);
  k_bias_cat<<<dim3(12), 256, 0, stream>>>(bq, bk, bv, bqkv);

  // 2) merged QKV GEMM: M=32768, N=3072, K=1024 + fused reductions
  k_g256<5><<<dim3(12, 128, 1), 512, 0, stream>>>(
      xh, Wqkvh, Qh, Kh, Vh, 1024, 0, 0, 0, bqkv,
      pq, qsum, pk, Vsum, nullptr, nullptr, nullptr, nullptr);

  // 3) inverse norms
  k_norms_fin<<<dim3(64), 256, 0, stream>>>(pq, pk, invq, invk);

  // 4) KnT = T(Kh)*invk   (before QT overlays Kh)
  k_transpose_scale<<<dim3(32, 16, 16), 256, 0, stream>>>(Kh, invk, KnT);

  // 5) QT = T(Qh)*invq    (overlays Kh)
  k_transpose_scale<<<dim3(32, 16, 16), 256, 0, stream>>>(Qh, invq, QT);

  // 6) S = QT x KnT^T per batch (M=N=1024, K=2048) + row sums — overlays Qh
  k_g256<4><<<dim3(4, 4, 16), 512, 0, stream>>>(
      QT, KnT, S, nullptr, nullptr, 2048, 1024L * 2048, 1024L * 2048, 1024L * 1024,
      nullptr, nullptr, nullptr, nullptr, Srow, nullptr, nullptr, nullptr, nullptr);

  // 7) tailor
  k_tailor_fin<<<dim3(64), 256, 0, stream>>>(Srow, invq, qsum, tailor);

  // 8) out = xh + gamma*(Vsum + V x S^T) * tailor   (M=2048/batch, N=1024, K=1024)
  k_g256<1><<<dim3(4, 8, 16), 512, 0, stream>>>(
      Vh, S, d_out, nullptr, nullptr, 1024, 2048L * 1024, 1024L * 1024, 2048L * 1024,
      nullptr, nullptr, nullptr, nullptr, nullptr, xh, Vsum, tailor, gamma);
}